// Round 1
// baseline (534.299 us; speedup 1.0000x reference)
//
#include <hip/hip_runtime.h>

// Problem geometry (compile-time constants, from the reference):
//   E_TOTAL=16, E_CACHE=8, HIDDEN=1024, INTER=2048
// Output = concat(w13_cache, w13_bias_cache, w2_cache, w2_bias_cache) flat f32.
//
// float4 units:
//   w13      per-slot: 2*INTER*HIDDEN/4   = 1,048,576  (shift 20)
//   w13_bias per-slot: 2*INTER/4          = 1,024      (shift 10)
//   w2       per-slot: HIDDEN*INTER/4     = 524,288    (shift 19)
//   w2_bias  per-slot: HIDDEN/4           = 256        (shift 8)
// Section boundaries (float4, cumulative over 8 slots):
//   B0 = 8*1048576           = 8,388,608
//   B1 = B0 + 8*1024         = 8,396,800
//   B2 = B1 + 8*524288       = 12,591,104
//   B3 = B2 + 8*256          = 12,593,152   (total)

#define ECACHE 8

__global__ void resolve_slots(const int* __restrict__ expert_ids,
                              const int* __restrict__ slot_ids,
                              int* __restrict__ slot_src) {
    int t = threadIdx.x;
    if (t < ECACHE) {
        int src = -1;
        // last pair wins (scatter-set semantics with duplicate slot ids)
        for (int s = 0; s < ECACHE; ++s) {
            if (slot_ids[s] == t) src = expert_ids[s];
        }
        slot_src[t] = src;
    }
}

__global__ __launch_bounds__(256) void gather_scatter_copy(
    const float4* __restrict__ w13_src,
    const float4* __restrict__ w13b_src,
    const float4* __restrict__ w2_src,
    const float4* __restrict__ w2b_src,
    const float4* __restrict__ w13_c,
    const float4* __restrict__ w13b_c,
    const float4* __restrict__ w2_c,
    const float4* __restrict__ w2b_c,
    const int* __restrict__ slot_src,
    float4* __restrict__ out) {

    const int B0 = 8388608;
    const int B1 = 8396800;
    const int B2 = 12591104;
    const int B3 = 12593152;

    int stride = gridDim.x * blockDim.x;
    for (int i = blockIdx.x * blockDim.x + threadIdx.x; i < B3; i += stride) {
        float4 v;
        if (i < B0) {                       // w13: per-slot 2^20 float4
            int j = i;
            int slot = j >> 20;
            int off  = j & ((1 << 20) - 1);
            int e = slot_src[slot];
            v = (e >= 0) ? w13_src[((long)e << 20) + off] : w13_c[j];
        } else if (i < B1) {                // w13_bias: per-slot 2^10 float4
            int j = i - B0;
            int slot = j >> 10;
            int off  = j & ((1 << 10) - 1);
            int e = slot_src[slot];
            v = (e >= 0) ? w13b_src[(e << 10) + off] : w13b_c[j];
        } else if (i < B2) {                // w2: per-slot 2^19 float4
            int j = i - B1;
            int slot = j >> 19;
            int off  = j & ((1 << 19) - 1);
            int e = slot_src[slot];
            v = (e >= 0) ? w2_src[((long)e << 19) + off] : w2_c[j];
        } else {                            // w2_bias: per-slot 2^8 float4
            int j = i - B2;
            int slot = j >> 8;
            int off  = j & ((1 << 8) - 1);
            int e = slot_src[slot];
            v = (e >= 0) ? w2b_src[(e << 8) + off] : w2b_c[j];
        }
        out[i] = v;
    }
}

extern "C" void kernel_launch(void* const* d_in, const int* in_sizes, int n_in,
                              void* d_out, int out_size, void* d_ws, size_t ws_size,
                              hipStream_t stream) {
    const float4* w13_src  = (const float4*)d_in[0];
    const float4* w13b_src = (const float4*)d_in[1];
    const float4* w2_src   = (const float4*)d_in[2];
    const float4* w2b_src  = (const float4*)d_in[3];
    const float4* w13_c    = (const float4*)d_in[4];
    const float4* w13b_c   = (const float4*)d_in[5];
    const float4* w2_c     = (const float4*)d_in[6];
    const float4* w2b_c    = (const float4*)d_in[7];
    const int* expert_ids  = (const int*)d_in[8];
    const int* slot_ids    = (const int*)d_in[9];

    int* slot_src = (int*)d_ws;   // 8 ints; d_ws is re-poisoned each call, so
                                  // resolve_slots must run every launch (it does).

    resolve_slots<<<1, 64, 0, stream>>>(expert_ids, slot_ids, slot_src);

    // memory-bound: ~2048 blocks, grid-stride
    const int blocks = 2048;
    gather_scatter_copy<<<blocks, 256, 0, stream>>>(
        w13_src, w13b_src, w2_src, w2b_src,
        w13_c, w13b_c, w2_c, w2b_c,
        slot_src, (float4*)d_out);
}